// Round 7
// baseline (173.968 us; speedup 1.0000x reference)
//
#include <hip/hip_runtime.h>

#define N_NODES 100000
#define N_EDGES 800000
#define EHALF (N_EDGES / 2)
#define H 128
#define MAX_Z 1000
#define N_GRAPHS 500
#define ELL_CAP 32
#define EB 1563                  // edge blocks: ceil(400000/256), 2 edges/thread
#define SCAP 66                  // 2 centers + 2*32 neighbor rows
#define TCAP 2178                // exact bound: SCAP * (1 + ELL_CAP)

typedef __attribute__((ext_vector_type(8))) short bf16x8;
typedef __attribute__((ext_vector_type(4))) float f32x4;

__device__ __forceinline__ unsigned short f2bf(float f) {
    union { float f; unsigned u; } x; x.f = f;
    unsigned r = x.u + 0x7fffu + ((x.u >> 16) & 1u);   // RTNE
    return (unsigned short)(r >> 16);
}
__device__ __forceinline__ float bf2f(unsigned short u) {
    return __uint_as_float((unsigned)u << 16);
}
__device__ __forceinline__ int clampid(int p) {       // poison (0xAA..) is negative
    return (p < 0 || p >= N_NODES) ? 0 : p;
}

// ---- P1: deg count (fire-and-forget) + N1 flags + T0 GEMM + W1 pack ------
// NO returning atomics anywhere in this pass -> no wave stalls on the RMW.
__global__ __launch_bounds__(256) void k_p1(const int* __restrict__ esrc,
                                            const int* __restrict__ edst,
                                            const int* __restrict__ mask,
                                            int* deg, int* f1,
                                            const float* __restrict__ ztab,
                                            const float* __restrict__ W0,
                                            const float* __restrict__ W1,
                                            unsigned short* Wp,
                                            unsigned short* T0) {
    int b = blockIdx.x, tid = threadIdx.x;
    if (b < EB) {
        int e = b * 256 + tid;
        if (e >= EHALF) return;
        int m0 = mask[e], m1 = mask[e + EHALF];
        int d0 = edst[e], d1 = edst[e + EHALF];
        int s0 = esrc[e], s1 = esrc[e + EHALF];
        if (m0) atomicAdd(&deg[d0], 1);               // no-return path
        if (m1) atomicAdd(&deg[d1], 1);
        if (m0 && d0 % 200 < 2) f1[s0] = 1;           // plain stores
        if (m1 && d1 % 200 < 2) f1[s1] = 1;
    } else if (b < EB + 63) {
        // T0 GEMM tile t (0..62): fp32 ztab/W0 -> bf16 in-register -> MFMA
        int t = b - EB;
        int lane = tid & 63, wv = tid >> 6;
        int m = lane & 15, quad = lane >> 4;
        int row = t * 16 + m;
        const float* ar = ztab + (size_t)(row < MAX_Z ? row : 0) * H + quad * 8;
        bf16x8 A[4];
#pragma unroll
        for (int kk = 0; kk < 4; kk++) {
            float4 u  = *(const float4*)(ar + kk * 32);
            float4 v4 = *(const float4*)(ar + kk * 32 + 4);
            bf16x8 aa;
            aa[0] = (short)f2bf(u.x);  aa[1] = (short)f2bf(u.y);
            aa[2] = (short)f2bf(u.z);  aa[3] = (short)f2bf(u.w);
            aa[4] = (short)f2bf(v4.x); aa[5] = (short)f2bf(v4.y);
            aa[6] = (short)f2bf(v4.z); aa[7] = (short)f2bf(v4.w);
            A[kk] = aa;
        }
#pragma unroll
        for (int c2 = 0; c2 < 2; c2++) {
            int c = wv * 2 + c2;
            int n = c * 16 + m;
            f32x4 acc = (f32x4){0.f, 0.f, 0.f, 0.f};
#pragma unroll
            for (int kt = 0; kt < 4; kt++) {
                bf16x8 bb;
#pragma unroll
                for (int j = 0; j < 8; j++)
                    bb[j] = (short)f2bf(W0[(size_t)(kt * 32 + quad * 8 + j) * H + n]);
                acc = __builtin_amdgcn_mfma_f32_16x16x32_bf16(A[kt], bb, acc, 0, 0, 0);
            }
            int r0 = t * 16 + quad * 4;
#pragma unroll
            for (int i2 = 0; i2 < 4; i2++) {
                int r = r0 + i2;
                if (r < MAX_Z) T0[(size_t)r * H + n] = f2bf(acc[i2]);
            }
        }
    } else if (b < EB + 71) {
        int bb = b - EB - 63;                          // 0..7: pack W1
        int t = bb * 256 + tid;                        // 0..2047
        int l = t & 63, kt = (t >> 6) & 3, c = t >> 8;
        int quad = l >> 4, n = c * 16 + (l & 15);
        unsigned short o[8];
#pragma unroll
        for (int j = 0; j < 8; j++) o[j] = f2bf(W1[(kt * 32 + quad * 8 + j) * H + n]);
        ushort4 lo = { o[0], o[1], o[2], o[3] }, hi = { o[4], o[5], o[6], o[7] };
        unsigned short* dst = Wp + (size_t)t * 8;
        *(ushort4*)(dst)     = lo;
        *(ushort4*)(dst + 4) = hi;
    } else {
        int i = (b - EB - 71) * 256 + tid;             // centers always in N1
        if (i < 2 * N_GRAPHS) f1[(i >> 1) * 200 + (i & 1)] = 1;
    }
}

// ---- P2: build annotated ELL rows for f1 nodes; flag their sources f0 ----
// Entry = (src, z[src], rsqrt(1+deg[src])): deg is final after P1, so the
// coefficient is precomputed here, removing 2 gather-hops from every
// downstream x1 evaluation.
__global__ __launch_bounds__(256) void k_p2(const int* __restrict__ esrc,
                                            const int* __restrict__ edst,
                                            const int* __restrict__ mask,
                                            const int* __restrict__ z,
                                            const int* __restrict__ deg,
                                            const int* __restrict__ f1,
                                            int* f0, int* cur, int* ell,
                                            unsigned short* ellz, float* ellc) {
    int e = blockIdx.x * 256 + threadIdx.x;
    if (e >= EHALF) return;
    int m0 = mask[e], m1 = mask[e + EHALF];
    int d0 = edst[e], d1 = edst[e + EHALF];
    int s0 = esrc[e], s1 = esrc[e + EHALF];
    int fa = f1[d0], fb = f1[d1];
    bool q0 = m0 && fa, q1 = m1 && fb;
    int z0 = 0, z1 = 0, g0 = 0, g1 = 0;
    if (q0) { z0 = z[s0]; g0 = deg[s0]; f0[s0] = 1; }
    if (q1) { z1 = z[s1]; g1 = deg[s1]; f0[s1] = 1; }
    int c0 = 0, c1 = 0;
    if (q0) c0 = atomicAdd(&cur[d0], 1);
    if (q1) c1 = atomicAdd(&cur[d1], 1);
    if (q0 && c0 < ELL_CAP) {
        size_t o = (size_t)d0 * ELL_CAP + c0;
        ell[o] = s0; ellz[o] = (unsigned short)z0; ellc[o] = rsqrtf(1.f + (float)g0);
    }
    if (q1 && c1 < ELL_CAP) {
        size_t o = (size_t)d1 * ELL_CAP + c1;
        ell[o] = s1; ellz[o] = (unsigned short)z1; ellc[o] = rsqrtf(1.f + (float)g1);
    }
}

// ---- P3: build annotated ELL rows for f0 \ f1 nodes ----------------------
__global__ __launch_bounds__(256) void k_p3(const int* __restrict__ esrc,
                                            const int* __restrict__ edst,
                                            const int* __restrict__ mask,
                                            const int* __restrict__ z,
                                            const int* __restrict__ deg,
                                            const int* __restrict__ f1,
                                            const int* __restrict__ f0,
                                            int* cur, int* ell,
                                            unsigned short* ellz, float* ellc) {
    int e = blockIdx.x * 256 + threadIdx.x;
    if (e >= EHALF) return;
    int m0 = mask[e], m1 = mask[e + EHALF];
    int d0 = edst[e], d1 = edst[e + EHALF];
    int s0 = esrc[e], s1 = esrc[e + EHALF];
    bool q0 = m0 && f0[d0] && !f1[d0];
    bool q1 = m1 && f0[d1] && !f1[d1];
    int z0 = 0, z1 = 0, g0 = 0, g1 = 0;
    if (q0) { z0 = z[s0]; g0 = deg[s0]; }
    if (q1) { z1 = z[s1]; g1 = deg[s1]; }
    int c0 = 0, c1 = 0;
    if (q0) c0 = atomicAdd(&cur[d0], 1);
    if (q1) c1 = atomicAdd(&cur[d1], 1);
    if (q0 && c0 < ELL_CAP) {
        size_t o = (size_t)d0 * ELL_CAP + c0;
        ell[o] = s0; ellz[o] = (unsigned short)z0; ellc[o] = rsqrtf(1.f + (float)g0);
    }
    if (q1 && c1 < ELL_CAP) {
        size_t o = (size_t)d1 * ELL_CAP + c1;
        ell[o] = s1; ellz[o] = (unsigned short)z1; ellc[o] = rsqrtf(1.f + (float)g1);
    }
}

// ---- k_fused v2: one block per graph, flat-task x1 evaluation ------------
__global__ __launch_bounds__(512) void k_fused(const int* __restrict__ z,
                                               const unsigned short* __restrict__ T0,
                                               const int* __restrict__ ell,
                                               const unsigned short* __restrict__ ellz,
                                               const float* __restrict__ ellc,
                                               const int* __restrict__ deg,
                                               const unsigned short* __restrict__ Wp1,
                                               const float* __restrict__ b0,
                                               const float* __restrict__ b1,
                                               const float* __restrict__ W2,
                                               const float* __restrict__ b2,
                                               const float* __restrict__ l1w,
                                               const float* __restrict__ l1b,
                                               const float* __restrict__ l2w,
                                               const float* __restrict__ l2b,
                                               float* __restrict__ out) {
    __shared__ float xy[SCAP][132];          // y1 accumulators, then x2
    __shared__ unsigned short yt[16][136];   // bf16 MFMA A staging
    __shared__ unsigned int taskA[TCAP];     // u | r<<17 | n<<24
    __shared__ float taskB[TCAP];            // dv_u = rsqrt(1+deg[u])
    __shared__ int   Sv[SCAP];
    __shared__ float Sdv[SCAP];
    __shared__ int   Snv[SCAP];
    __shared__ float Scoef[SCAP];
    __shared__ float y2s[2][128];
    __shared__ float x3s[2][128];
    __shared__ float hsum[4][128];
    __shared__ float hpart[2];
    __shared__ int tcnt, scnts, n0s;

    int g = blockIdx.x;
    int tid = threadIdx.x, lane = tid & 63, wv = tid >> 6;   // 8 waves
    int l2 = lane * 2;
    float2 bv = *(const float2*)(b0 + l2);

    // ---- phase 0: wave 0 builds row metadata; waves 1-7 zero xy ----
    if (wv == 0) {
        int half = lane >> 5, li = lane & 31;
        int c = g * 200 + half;
        int degc = deg[c];
        int u  = ell[(size_t)c * ELL_CAP + li];
        float ecv = ellc[(size_t)c * ELL_CAP + li];
        int nc = degc > ELL_CAP ? ELL_CAP : degc;
        float dvc = rsqrtf(1.f + (float)degc);
        int uc = clampid(u);
        int degu = deg[uc];
        int nc0 = __shfl(nc, 0), nc1 = __shfl(nc, 32);
        int base = 2 + (half ? nc0 : 0);
        if (li < nc) {
            Sv[base + li]    = uc;
            Sdv[base + li]   = ecv;                       // = rsqrt(1+deg[u])
            Snv[base + li]   = degu > ELL_CAP ? ELL_CAP : degu;
            Scoef[base + li] = ecv * dvc;
        }
        if (lane == 0)  { Sv[0] = c; Sdv[0] = dvc; Snv[0] = nc;
                          scnts = 2 + nc0 + nc1; n0s = nc0; tcnt = 0; }
        if (lane == 32) { Sv[1] = c; Sdv[1] = dvc; Snv[1] = nc; }
    } else {
        for (int i = tid - 64; i < SCAP * 132; i += 448)
            ((float*)xy)[i] = 0.f;
    }
    __syncthreads();
    const int scnt = scnts;

    // ---- phase 0.5: build flat task list (row, u, n, dv_u) ----
    for (int r = wv; r < scnt; r += 8) {
        int v = Sv[r]; int nv = Snv[r]; float dvv = Sdv[r];
        int u = 0; float ec = 0.f;
        if (lane < nv) {
            u  = ell[(size_t)v * ELL_CAP + lane];
            ec = ellc[(size_t)v * ELL_CAP + lane];
        }
        int uc = clampid(u);
        int du = (lane < nv) ? deg[uc] : 0;
        int base = 0;
        if (lane == 0) base = atomicAdd(&tcnt, nv + 1);
        base = __shfl(base, 0);
        if (lane < nv) {
            int nn = du > ELL_CAP ? ELL_CAP : du;
            taskA[base + lane] = (unsigned)uc | ((unsigned)r << 17) | ((unsigned)nn << 24);
            taskB[base + lane] = ec;
        }
        if (lane == 0) {
            taskA[base + nv] = (unsigned)v | ((unsigned)r << 17) | ((unsigned)nv << 24);
            taskB[base + nv] = dvv;
        }
    }
    __syncthreads();
    const int tc = tcnt;

    // ---- phase 1: evaluate tasks in pairs across all 8 waves ----
    for (int p = wv; 2 * p < tc; p += 8) {
        int t0 = 2 * p, t1 = 2 * p + 1;
        bool v1 = t1 < tc;
        unsigned a0w = taskA[t0];
        unsigned a1w = v1 ? taskA[t1] : a0w;
        float dv0 = taskB[t0];
        float dv1 = v1 ? taskB[t1] : 0.f;
        int u0 = a0w & 0x1FFFF, r0 = (a0w >> 17) & 0x7F, n0 = (a0w >> 24) & 0x3F;
        int u1 = a1w & 0x1FFFF, r1 = (a1w >> 17) & 0x7F;
        int n1 = v1 ? (int)((a1w >> 24) & 0x3F) : 0;
        int half = lane >> 5, li = lane & 31;
        int uu = half ? u1 : u0;
        float ec = ellc[(size_t)uu * ELL_CAP + li];          // hop 1
        int   ez = (int)ellz[(size_t)uu * ELL_CAP + li];
        int  zvv = z[uu];
        int z0 = __shfl(zvv, 0), z1 = __shfl(zvv, 32);
        ushort2 sa = *(const ushort2*)(T0 + (size_t)z0 * H + l2);   // hop 2
        ushort2 sb = *(const ushort2*)(T0 + (size_t)z1 * H + l2);
        float aAx = bv.x, aAy = bv.y, aBx = bv.x, aBy = bv.y;
        int kmax = n0 > n1 ? n0 : n1;
        int k = 0;
        for (; k + 1 < kmax; k += 2) {
            int za0 = __shfl(ez, k),      za1 = __shfl(ez, k + 1);
            int zb0 = __shfl(ez, 32 + k), zb1 = __shfl(ez, 32 + k + 1);
            za0 = za0 < MAX_Z ? za0 : 0;  za1 = za1 < MAX_Z ? za1 : 0;
            zb0 = zb0 < MAX_Z ? zb0 : 0;  zb1 = zb1 < MAX_Z ? zb1 : 0;
            float ca0 = (k < n0)     ? __shfl(ec, k) * dv0      : 0.f;
            float ca1 = (k + 1 < n0) ? __shfl(ec, k + 1) * dv0  : 0.f;
            float cb0 = (k < n1)     ? __shfl(ec, 32 + k) * dv1 : 0.f;
            float cb1 = (k + 1 < n1) ? __shfl(ec, 32 + k + 1) * dv1 : 0.f;
            ushort2 A0 = *(const ushort2*)(T0 + (size_t)za0 * H + l2);
            ushort2 A1 = *(const ushort2*)(T0 + (size_t)za1 * H + l2);
            ushort2 B0 = *(const ushort2*)(T0 + (size_t)zb0 * H + l2);
            ushort2 B1 = *(const ushort2*)(T0 + (size_t)zb1 * H + l2);
            aAx += ca0 * bf2f(A0.x) + ca1 * bf2f(A1.x);
            aAy += ca0 * bf2f(A0.y) + ca1 * bf2f(A1.y);
            aBx += cb0 * bf2f(B0.x) + cb1 * bf2f(B1.x);
            aBy += cb0 * bf2f(B0.y) + cb1 * bf2f(B1.y);
        }
        if (k < kmax) {
            int za0 = __shfl(ez, k), zb0 = __shfl(ez, 32 + k);
            za0 = za0 < MAX_Z ? za0 : 0;  zb0 = zb0 < MAX_Z ? zb0 : 0;
            float ca0 = (k < n0) ? __shfl(ec, k) * dv0 : 0.f;
            float cb0 = (k < n1) ? __shfl(ec, 32 + k) * dv1 : 0.f;
            ushort2 A0 = *(const ushort2*)(T0 + (size_t)za0 * H + l2);
            ushort2 B0 = *(const ushort2*)(T0 + (size_t)zb0 * H + l2);
            aAx += ca0 * bf2f(A0.x); aAy += ca0 * bf2f(A0.y);
            aBx += cb0 * bf2f(B0.x); aBy += cb0 * bf2f(B0.y);
        }
        aAx += dv0 * dv0 * bf2f(sa.x); aAy += dv0 * dv0 * bf2f(sa.y);
        aBx += dv1 * dv1 * bf2f(sb.x); aBy += dv1 * dv1 * bf2f(sb.y);
        aAx = fmaxf(aAx, 0.f); aAy = fmaxf(aAy, 0.f);    // relu(x1)
        aBx = fmaxf(aBx, 0.f); aBy = fmaxf(aBy, 0.f);
        float c0 = dv0 * Sdv[r0];
        atomicAdd(&xy[r0][l2],     c0 * aAx);
        atomicAdd(&xy[r0][l2 + 1], c0 * aAy);
        if (v1) {
            float c1 = dv1 * Sdv[r1];
            atomicAdd(&xy[r1][l2],     c1 * aBx);
            atomicAdd(&xy[r1][l2 + 1], c1 * aBy);
        }
    }
    __syncthreads();

    // ---- phase 2: x2 = relu(y1 @ W1 + b1) via MFMA tiles (in-place) ----
    int m = lane & 15, quad = lane >> 4;
    int tiles = (scnt + 15) >> 4;
    for (int t = 0; t < tiles; ++t) {
        for (int q = 0; q < 2; q++) {
            int r = t * 16 + wv * 2 + q;
            float vx = 0.f, vy = 0.f;
            if (r < scnt) { vx = xy[r][l2]; vy = xy[r][l2 + 1]; }
            ushort2 o; o.x = f2bf(vx); o.y = f2bf(vy);
            *(ushort2*)&yt[wv * 2 + q][l2] = o;
        }
        __syncthreads();
        bf16x8 a0 = *(const bf16x8*)&yt[m][quad * 8];
        bf16x8 a1 = *(const bf16x8*)&yt[m][32 + quad * 8];
        bf16x8 a2 = *(const bf16x8*)&yt[m][64 + quad * 8];
        bf16x8 a3 = *(const bf16x8*)&yt[m][96 + quad * 8];
        const unsigned short* bp = Wp1 + ((size_t)(wv * 4) * 64 + lane) * 8;
        bf16x8 b0f = *(const bf16x8*)(bp);
        bf16x8 b1f = *(const bf16x8*)(bp + 512);
        bf16x8 b2f = *(const bf16x8*)(bp + 1024);
        bf16x8 b3f = *(const bf16x8*)(bp + 1536);
        f32x4 a = (f32x4){0.f, 0.f, 0.f, 0.f};
        a = __builtin_amdgcn_mfma_f32_16x16x32_bf16(a0, b0f, a, 0, 0, 0);
        a = __builtin_amdgcn_mfma_f32_16x16x32_bf16(a1, b1f, a, 0, 0, 0);
        a = __builtin_amdgcn_mfma_f32_16x16x32_bf16(a2, b2f, a, 0, 0, 0);
        a = __builtin_amdgcn_mfma_f32_16x16x32_bf16(a3, b3f, a, 0, 0, 0);
        int r0 = t * 16 + quad * 4;
        int col = wv * 16 + m;
        float bb1 = b1[col];
#pragma unroll
        for (int i2 = 0; i2 < 4; i2++) {
            int r = r0 + i2;
            if (r < scnt) xy[r][col] = fmaxf(a[i2] + bb1, 0.f);
        }
        __syncthreads();
    }

    // ---- phase 3: y2 at the 2 centers from x2 rows ----
    if (tid < 256) {
        int c = tid >> 7, j = tid & 127;
        float dvc = Sdv[c];
        float acc = dvc * dvc * xy[c][j];
        int nc = Snv[c];
        int off = 2 + (c ? n0s : 0);
        for (int k = 0; k < nc; k++) acc += Scoef[off + k] * xy[off + k][j];
        y2s[c][j] = acc;
    }
    __syncthreads();

    // ---- phase 4: x3 = y2 @ W2 + b2 (f32 VALU, 256 threads) --------------
    // (round-6 bug: the 4-wave MFMA tile was pasted into this 8-wave kernel;
    //  waves 4-7 produced col in [128,256) -> OOB Wp2 reads + x3s[0] writes
    //  aliasing x3s[1]. Reverted to the round-5 f32 path: absmax was 0.0.)
    if (tid < 256) {
        int c = tid >> 7, j = tid & 127;
        float acc = b2[j];
#pragma unroll 4
        for (int k = 0; k < H; k++) acc += y2s[c][k] * W2[(size_t)k * H + j];
        x3s[c][j] = acc;
    }
    __syncthreads();

    // ---- phase 5: hadamard + MLP head, split-k over all 512 threads ----
    {
        int kq = tid >> 7, j = tid & 127;
        float acc = 0.f;
#pragma unroll 4
        for (int k = kq * 32; k < kq * 32 + 32; k++) {
            float pk = x3s[0][k] * x3s[1][k];
            acc += pk * l1w[(size_t)k * H + j];
        }
        hsum[kq][j] = acc;
    }
    __syncthreads();
    if (tid < 128) {
        float h = hsum[0][tid] + hsum[1][tid] + hsum[2][tid] + hsum[3][tid] + l1b[tid];
        float tv = fmaxf(h, 0.f) * l2w[tid];
#pragma unroll
        for (int d = 32; d > 0; d >>= 1) tv += __shfl_xor(tv, d);
        if (lane == 0) hpart[wv] = tv;
    }
    __syncthreads();
    if (tid == 0) out[g] = hpart[0] + hpart[1] + l2b[0];
}

extern "C" void kernel_launch(void* const* d_in, const int* in_sizes, int n_in,
                              void* d_out, int out_size, void* d_ws, size_t ws_size,
                              hipStream_t stream) {
    const int*   z    = (const int*)d_in[0];
    const int*   esrc = (const int*)d_in[1];
    const int*   edst = ((const int*)d_in[1]) + N_EDGES;
    const int*   mask = (const int*)d_in[3];
    const float* ztab = (const float*)d_in[4];
    const float* W0   = (const float*)d_in[5];
    const float* b0   = (const float*)d_in[6];
    const float* W1   = (const float*)d_in[7];
    const float* b1   = (const float*)d_in[8];
    const float* W2   = (const float*)d_in[9];
    const float* b2   = (const float*)d_in[10];
    const float* l1w  = (const float*)d_in[11];
    const float* l1b  = (const float*)d_in[12];
    const float* l2w  = (const float*)d_in[13];
    const float* l2b  = (const float*)d_in[14];
    float* out = (float*)d_out;

    char* w = (char*)d_ws;
    size_t o = 0;
    auto carve = [&](size_t bytes) { char* p = w + o; o = (o + bytes + 255) & ~(size_t)255; return p; };
    // zero-group first: one memset covers deg + cur + f1 + f0
    int*            deg  = (int*)carve((size_t)N_NODES * 4);
    int*            cur  = (int*)carve((size_t)N_NODES * 4);
    int*            f1   = (int*)carve((size_t)N_NODES * 4);
    int*            f0   = (int*)carve((size_t)N_NODES * 4);
    const size_t zero_span = o;
    int*            ell  = (int*)carve((size_t)N_NODES * ELL_CAP * 4);
    unsigned short* ellz = (unsigned short*)carve((size_t)N_NODES * ELL_CAP * 2);
    float*          ellc = (float*)carve((size_t)N_NODES * ELL_CAP * 4);
    unsigned short* Wp   = (unsigned short*)carve((size_t)16384 * 2);   // W1 frags
    unsigned short* T0   = (unsigned short*)carve((size_t)MAX_Z * H * 2);

    hipMemsetAsync(d_ws, 0, zero_span, stream);
    // P1: deg (no-return atomics) + N1 flags + T0 GEMM + W1 pack
    k_p1<<<EB + 63 + 8 + 4, 256, 0, stream>>>(esrc, edst, mask, deg, f1,
                                              ztab, W0, W1, Wp, T0);
    // P2: annotated ELL for f1 rows (+f0 flags)
    k_p2<<<EB, 256, 0, stream>>>(esrc, edst, mask, z, deg, f1, f0, cur,
                                 ell, ellz, ellc);
    // P3: annotated ELL for f0 \ f1 rows
    k_p3<<<EB, 256, 0, stream>>>(esrc, edst, mask, z, deg, f1, f0, cur,
                                 ell, ellz, ellc);
    // back half: one block per graph
    k_fused<<<N_GRAPHS, 512, 0, stream>>>(z, T0, ell, ellz, ellc, deg,
                                          Wp, b0, b1, W2, b2,
                                          l1w, l1b, l2w, l2b, out);
}

// Round 8
// 154.976 us; speedup vs baseline: 1.1225x; 1.1225x over previous
//
#include <hip/hip_runtime.h>

#define N_NODES 100000
#define N_EDGES 800000
#define H 128
#define MAX_Z 1000
#define N_GRAPHS 500
#define ELL_CAP 32
#define SB 782                   // edge scan blocks: ceil(800000/(256*4))
#define SSTRIDE (SB * 256)       // 200192 threads, 4 edges each
#define SCAPC 33                 // 1 center + 32 neighbor rows

typedef __attribute__((ext_vector_type(8))) short bf16x8;
typedef __attribute__((ext_vector_type(4))) float f32x4;

__device__ __forceinline__ unsigned short f2bf(float f) {
    union { float f; unsigned u; } x; x.f = f;
    unsigned r = x.u + 0x7fffu + ((x.u >> 16) & 1u);   // RTNE
    return (unsigned short)(r >> 16);
}
__device__ __forceinline__ float bf2f(unsigned short u) {
    return __uint_as_float((unsigned)u << 16);
}
__device__ __forceinline__ int clampid(int p) {       // poison (0xAA..) is negative
    return (p < 0 || p >= N_NODES) ? 0 : p;
}

// ---- k_scan: ELL build with 4-edge ILP + T0 GEMM + W1 pack (round-5) -----
__global__ __launch_bounds__(256) void k_scan(const int* __restrict__ esrc,
                                              const int* __restrict__ edst,
                                              const int* __restrict__ mask,
                                              int* fill, int* ell,
                                              const float* __restrict__ ztab,
                                              const float* __restrict__ W0,
                                              const float* __restrict__ W1,
                                              unsigned short* Wp,
                                              unsigned short* T0) {
    int b = blockIdx.x, tid = threadIdx.x;
    if (b < SB) {
        int e0 = b * 256 + tid;
        int e1 = e0 + SSTRIDE, e2 = e0 + 2 * SSTRIDE, e3 = e0 + 3 * SSTRIDE;
        int m0 = mask[e0], m1 = mask[e1], m2 = mask[e2];
        int m3 = (e3 < N_EDGES) ? mask[e3] : 0;
        int d0 = edst[e0], d1 = edst[e1], d2 = edst[e2];
        int d3 = (e3 < N_EDGES) ? edst[e3] : 0;
        int s0 = esrc[e0], s1 = esrc[e1], s2 = esrc[e2];
        int s3 = (e3 < N_EDGES) ? esrc[e3] : 0;
        int q0 = 0, q1 = 0, q2 = 0, q3 = 0;
        if (m0) q0 = atomicAdd(&fill[d0], 1);
        if (m1) q1 = atomicAdd(&fill[d1], 1);
        if (m2) q2 = atomicAdd(&fill[d2], 1);
        if (m3) q3 = atomicAdd(&fill[d3], 1);
        if (m0 && q0 < ELL_CAP) ell[(size_t)d0 * ELL_CAP + q0] = s0;
        if (m1 && q1 < ELL_CAP) ell[(size_t)d1 * ELL_CAP + q1] = s1;
        if (m2 && q2 < ELL_CAP) ell[(size_t)d2 * ELL_CAP + q2] = s2;
        if (m3 && q3 < ELL_CAP) ell[(size_t)d3 * ELL_CAP + q3] = s3;
    } else if (b < SB + 63) {
        // T0 GEMM tile t (0..62): fp32 ztab/W0 -> bf16 in-register -> MFMA
        int t = b - SB;
        int lane = tid & 63, wv = tid >> 6;
        int m = lane & 15, quad = lane >> 4;
        int row = t * 16 + m;
        const float* ar = ztab + (size_t)(row < MAX_Z ? row : 0) * H + quad * 8;
        bf16x8 A[4];
#pragma unroll
        for (int kk = 0; kk < 4; kk++) {
            float4 u  = *(const float4*)(ar + kk * 32);
            float4 v4 = *(const float4*)(ar + kk * 32 + 4);
            bf16x8 aa;
            aa[0] = (short)f2bf(u.x);  aa[1] = (short)f2bf(u.y);
            aa[2] = (short)f2bf(u.z);  aa[3] = (short)f2bf(u.w);
            aa[4] = (short)f2bf(v4.x); aa[5] = (short)f2bf(v4.y);
            aa[6] = (short)f2bf(v4.z); aa[7] = (short)f2bf(v4.w);
            A[kk] = aa;
        }
#pragma unroll
        for (int c2 = 0; c2 < 2; c2++) {
            int c = wv * 2 + c2;
            int n = c * 16 + m;
            f32x4 acc = (f32x4){0.f, 0.f, 0.f, 0.f};
#pragma unroll
            for (int kt = 0; kt < 4; kt++) {
                bf16x8 bb;
#pragma unroll
                for (int j = 0; j < 8; j++)
                    bb[j] = (short)f2bf(W0[(size_t)(kt * 32 + quad * 8 + j) * H + n]);
                acc = __builtin_amdgcn_mfma_f32_16x16x32_bf16(A[kt], bb, acc, 0, 0, 0);
            }
            int r0 = t * 16 + quad * 4;
#pragma unroll
            for (int i2 = 0; i2 < 4; i2++) {
                int r = r0 + i2;
                if (r < MAX_Z) T0[(size_t)r * H + n] = f2bf(acc[i2]);
            }
        }
    } else {
        int bb = b - SB - 63;                          // 0..7: pack W1
        int t = bb * 256 + tid;                        // 0..2047
        int l = t & 63, kt = (t >> 6) & 3, c = t >> 8;
        int quad = l >> 4, n = c * 16 + (l & 15);
        unsigned short o[8];
#pragma unroll
        for (int j = 0; j < 8; j++) o[j] = f2bf(W1[(kt * 32 + quad * 8 + j) * H + n]);
        ushort4 lo = { o[0], o[1], o[2], o[3] }, hi = { o[4], o[5], o[6], o[7] };
        unsigned short* dst = Wp + (size_t)t * 8;
        *(ushort4*)(dst)     = lo;
        *(ushort4*)(dst + 4) = hi;
    }
}

// ---- paired x1 evaluation (round-5, proven absmax 0.0) -------------------
__device__ __forceinline__ void x1_eval2(const int* __restrict__ z,
                                         const unsigned short* __restrict__ T0,
                                         const int* __restrict__ ell,
                                         const int* __restrict__ fill,
                                         int u0, int nt0, int u1, int nt1,
                                         int lane, int l2, float2 bv,
                                         float& r0x, float& r0y,
                                         float& r1x, float& r1y) {
    int na = nt0 > ELL_CAP ? ELL_CAP : nt0;
    int nb = nt1 > ELL_CAP ? ELL_CAP : nt1;
    float dva = rsqrtf(1.0f + (float)nt0);
    float dvb = rsqrtf(1.0f + (float)nt1);
    int pa = (lane < ELL_CAP) ? ell[(size_t)u0 * ELL_CAP + lane] : 0;
    int pb = (lane < ELL_CAP) ? ell[(size_t)u1 * ELL_CAP + lane] : 0;
    pa = clampid(pa); pb = clampid(pb);
    int za = z[pa], zb = z[pb];
    int fa = fill[pa], fb = fill[pb];
    int zu0 = z[u0], zu1 = z[u1];
    float pca = (lane < na) ? rsqrtf(1.0f + (float)fa) * dva : 0.f;
    float pcb = (lane < nb) ? rsqrtf(1.0f + (float)fb) * dvb : 0.f;
    ushort2 xa = *(const ushort2*)(T0 + (size_t)zu0 * H + l2);
    ushort2 xc = *(const ushort2*)(T0 + (size_t)zu1 * H + l2);
    r0x = dva * dva * bf2f(xa.x) + bv.x;
    r0y = dva * dva * bf2f(xa.y) + bv.y;
    r1x = dvb * dvb * bf2f(xc.x) + bv.x;
    r1y = dvb * dvb * bf2f(xc.y) + bv.y;
    int kmax = na > nb ? na : nb;
    int k = 0;
    for (; k + 1 < kmax; k += 2) {
        int za0 = __shfl(za, k), za1 = __shfl(za, k + 1);
        int zb0 = __shfl(zb, k), zb1 = __shfl(zb, k + 1);
        float ca0 = __shfl(pca, k), ca1 = __shfl(pca, k + 1);
        float cb0 = __shfl(pcb, k), cb1 = __shfl(pcb, k + 1);
        ushort2 A0 = *(const ushort2*)(T0 + (size_t)za0 * H + l2);
        ushort2 A1 = *(const ushort2*)(T0 + (size_t)za1 * H + l2);
        ushort2 B0 = *(const ushort2*)(T0 + (size_t)zb0 * H + l2);
        ushort2 B1 = *(const ushort2*)(T0 + (size_t)zb1 * H + l2);
        r0x += ca0 * bf2f(A0.x) + ca1 * bf2f(A1.x);
        r0y += ca0 * bf2f(A0.y) + ca1 * bf2f(A1.y);
        r1x += cb0 * bf2f(B0.x) + cb1 * bf2f(B1.x);
        r1y += cb0 * bf2f(B0.y) + cb1 * bf2f(B1.y);
    }
    if (k < kmax) {
        int za0 = __shfl(za, k), zb0 = __shfl(zb, k);
        float ca0 = __shfl(pca, k), cb0 = __shfl(pcb, k);
        ushort2 A0 = *(const ushort2*)(T0 + (size_t)za0 * H + l2);
        ushort2 B0 = *(const ushort2*)(T0 + (size_t)zb0 * H + l2);
        r0x += ca0 * bf2f(A0.x); r0y += ca0 * bf2f(A0.y);
        r1x += cb0 * bf2f(B0.x); r1y += cb0 * bf2f(B0.y);
    }
    r0x = fmaxf(r0x, 0.f); r0y = fmaxf(r0y, 0.f);
    r1x = fmaxf(r1x, 0.f); r1y = fmaxf(r1y, 0.f);
}

// ---- k_ctr: one block per CENTER (1000 blocks) ---------------------------
// S_c = {c} U nbrs(c) (<=33 rows, half the per-graph worst case); x2 rows via
// round-5's per-wave serial eval; y2(c); x3(c) = y2 @ W2 + b2 -> global.
__global__ __launch_bounds__(512) void k_ctr(const int* __restrict__ z,
                                             const unsigned short* __restrict__ T0,
                                             const int* __restrict__ ell,
                                             const int* __restrict__ fill,
                                             const unsigned short* __restrict__ Wp1,
                                             const float* __restrict__ b0,
                                             const float* __restrict__ b1,
                                             const float* __restrict__ W2,
                                             const float* __restrict__ b2,
                                             float* __restrict__ x3g) {
    __shared__ float x2s[SCAPC][132];
    __shared__ unsigned short yt[16][136];
    __shared__ float y2s[128];
    __shared__ int Sv[SCAPC];
    __shared__ float Scoef[SCAPC];
    __shared__ int scnts, n0s;
    __shared__ float sc0s;

    int bid = blockIdx.x;                    // 0..999
    int tid = threadIdx.x, lane = tid & 63, wv = tid >> 6;   // 8 waves
    int l2 = lane * 2;
    float2 bv = *(const float2*)(b0 + l2);

    // ---- phase 0 (wave 0): build S = {c} U nbrs(c) + y2 coefficients ----
    if (wv == 0) {
        int c = (bid >> 1) * 200 + (bid & 1);
        int ntc = fill[c];
        int nc = ntc > ELL_CAP ? ELL_CAP : ntc;
        float dvc = rsqrtf(1.0f + (float)ntc);
        int u = (lane < nc) ? ell[(size_t)c * ELL_CAP + lane] : 0;
        u = clampid(u);
        int fu = fill[u];
        if (lane < nc) {
            Sv[1 + lane]    = u;
            Scoef[1 + lane] = rsqrtf(1.0f + (float)fu) * dvc;
        }
        if (lane == 0) {
            Sv[0] = c; scnts = 1 + nc; n0s = nc; sc0s = dvc * dvc;
        }
    }
    __syncthreads();
    const int scnt = scnts;

    // ---- phase 1: x2[S] = relu( y1(S) @ W1 + b1 ), tiles of 16 rows ----
    int m = lane & 15, quad = lane >> 4;
    int tiles = (scnt + 15) >> 4;            // <= 3
    for (int t = 0; t < tiles; ++t) {
        for (int q = 0; q < 2; q++) {
            int r = t * 16 + wv * 2 + q;
            float ax = 0.f, ay = 0.f;
            if (r < scnt) {
                int v = Sv[r];
                int ntv = fill[v];
                int nv = ntv > ELL_CAP ? ELL_CAP : ntv;
                float dv = rsqrtf(1.0f + (float)ntv);
                int px = (lane < ELL_CAP) ? ell[(size_t)v * ELL_CAP + lane] : 0;
                px = clampid(px);
                int fx = fill[px];
                float pc = (lane < nv) ? rsqrtf(1.0f + (float)fx) * dv : 0.f;
                // pair 0: (self, nbr0)
                {
                    int u1 = __shfl(px, 0); int f1v = __shfl(fx, 0);
                    float cu = __shfl(pc, 0);
                    float r0x, r0y, r1x, r1y;
                    x1_eval2(z, T0, ell, fill, v, ntv, u1, f1v,
                             lane, l2, bv, r0x, r0y, r1x, r1y);
                    ax = dv * dv * r0x + cu * r1x;
                    ay = dv * dv * r0y + cu * r1y;
                }
                for (int k = 1; k < nv; k += 2) {
                    int ua = __shfl(px, k);     int fav = __shfl(fx, k);
                    float ca = __shfl(pc, k);
                    int kb = (k + 1 < nv) ? k + 1 : k;
                    int ub = __shfl(px, kb);    int fbv = __shfl(fx, kb);
                    float cb = (k + 1 < nv) ? __shfl(pc, k + 1) : 0.f;
                    float r0x, r0y, r1x, r1y;
                    x1_eval2(z, T0, ell, fill, ua, fav, ub, fbv,
                             lane, l2, bv, r0x, r0y, r1x, r1y);
                    ax += ca * r0x + cb * r1x;
                    ay += ca * r0y + cb * r1y;
                }
            }
            ushort2 o; o.x = f2bf(ax); o.y = f2bf(ay);
            *(ushort2*)&yt[wv * 2 + q][l2] = o;
        }
        __syncthreads();
        bf16x8 a0 = *(const bf16x8*)&yt[m][quad * 8];
        bf16x8 a1 = *(const bf16x8*)&yt[m][32 + quad * 8];
        bf16x8 a2 = *(const bf16x8*)&yt[m][64 + quad * 8];
        bf16x8 a3 = *(const bf16x8*)&yt[m][96 + quad * 8];
        const unsigned short* bp = Wp1 + ((size_t)(wv * 4) * 64 + lane) * 8;
        bf16x8 b0f = *(const bf16x8*)(bp);
        bf16x8 b1f = *(const bf16x8*)(bp + 512);
        bf16x8 b2f = *(const bf16x8*)(bp + 1024);
        bf16x8 b3f = *(const bf16x8*)(bp + 1536);
        f32x4 a = (f32x4){0.f, 0.f, 0.f, 0.f};
        a = __builtin_amdgcn_mfma_f32_16x16x32_bf16(a0, b0f, a, 0, 0, 0);
        a = __builtin_amdgcn_mfma_f32_16x16x32_bf16(a1, b1f, a, 0, 0, 0);
        a = __builtin_amdgcn_mfma_f32_16x16x32_bf16(a2, b2f, a, 0, 0, 0);
        a = __builtin_amdgcn_mfma_f32_16x16x32_bf16(a3, b3f, a, 0, 0, 0);
        int r0 = t * 16 + quad * 4;
        int col = wv * 16 + m;
        float bb1 = b1[col];
#pragma unroll
        for (int i2 = 0; i2 < 4; i2++) {
            int r = r0 + i2;
            if (r < scnt) x2s[r][col] = fmaxf(a[i2] + bb1, 0.f);
        }
        __syncthreads();
    }

    // ---- phase 2: y2(c) from x2 rows ----
    if (tid < 128) {
        int j = tid;
        float acc = sc0s * x2s[0][j];
        int nc = n0s;
        for (int k = 0; k < nc; k++) acc += Scoef[1 + k] * x2s[1 + k][j];
        y2s[j] = acc;
    }
    __syncthreads();

    // ---- phase 3: x3(c) = y2 @ W2 + b2 (f32 VALU, proven path) ----
    if (tid < 128) {
        int j = tid;
        float acc = b2[j];
#pragma unroll 4
        for (int k = 0; k < H; k++) acc += y2s[k] * W2[(size_t)k * H + j];
        x3g[(size_t)bid * H + j] = acc;
    }
}

// ---- k_head: hadamard + MLP head, one block per graph --------------------
__global__ __launch_bounds__(128) void k_head(const float* __restrict__ x3g,
                                              const float* __restrict__ l1w,
                                              const float* __restrict__ l1b,
                                              const float* __restrict__ l2w,
                                              const float* __restrict__ l2b,
                                              float* __restrict__ out) {
    __shared__ float p[128];
    __shared__ float hp[2];
    int g = blockIdx.x, tid = threadIdx.x, lane = tid & 63, wv = tid >> 6;
    p[tid] = x3g[(size_t)(2 * g) * H + tid] * x3g[(size_t)(2 * g + 1) * H + tid];
    __syncthreads();
    float h = l1b[tid];
#pragma unroll 4
    for (int k = 0; k < H; k++) h += p[k] * l1w[(size_t)k * H + tid];
    float tv = fmaxf(h, 0.f) * l2w[tid];
#pragma unroll
    for (int d = 32; d > 0; d >>= 1) tv += __shfl_xor(tv, d);
    if (lane == 0) hp[wv] = tv;
    __syncthreads();
    if (tid == 0) out[g] = hp[0] + hp[1] + l2b[0];
}

extern "C" void kernel_launch(void* const* d_in, const int* in_sizes, int n_in,
                              void* d_out, int out_size, void* d_ws, size_t ws_size,
                              hipStream_t stream) {
    const int*   z    = (const int*)d_in[0];
    const int*   esrc = (const int*)d_in[1];
    const int*   edst = ((const int*)d_in[1]) + N_EDGES;
    const int*   mask = (const int*)d_in[3];
    const float* ztab = (const float*)d_in[4];
    const float* W0   = (const float*)d_in[5];
    const float* b0   = (const float*)d_in[6];
    const float* W1   = (const float*)d_in[7];
    const float* b1   = (const float*)d_in[8];
    const float* W2   = (const float*)d_in[9];
    const float* b2   = (const float*)d_in[10];
    const float* l1w  = (const float*)d_in[11];
    const float* l1b  = (const float*)d_in[12];
    const float* l2w  = (const float*)d_in[13];
    const float* l2b  = (const float*)d_in[14];
    float* out = (float*)d_out;

    char* w = (char*)d_ws;
    size_t o = 0;
    auto carve = [&](size_t bytes) { char* p = w + o; o = (o + bytes + 255) & ~(size_t)255; return p; };
    int*            fill = (int*)carve((size_t)N_NODES * 4);     // must be zeroed
    const size_t zero_span = o;
    int*            ell  = (int*)carve((size_t)N_NODES * ELL_CAP * 4);
    unsigned short* Wp   = (unsigned short*)carve((size_t)16384 * 2);   // W1 frags
    unsigned short* T0   = (unsigned short*)carve((size_t)MAX_Z * H * 2);
    float*          x3g  = (float*)carve((size_t)2 * N_GRAPHS * H * 4);

    hipMemsetAsync(d_ws, 0, zero_span, stream);
    // pass 1: ELL build (4-edge ILP) + T0 GEMM + W1 pack  (round-5 verbatim)
    k_scan<<<SB + 63 + 8, 256, 0, stream>>>(esrc, edst, mask, fill, ell,
                                            ztab, W0, W1, Wp, T0);
    // pass 2: one block per CENTER -> x3g[1000][128]
    k_ctr<<<2 * N_GRAPHS, 512, 0, stream>>>(z, T0, ell, fill, Wp, b0, b1,
                                            W2, b2, x3g);
    // pass 3: hadamard + MLP head per graph
    k_head<<<N_GRAPHS, 128, 0, stream>>>(x3g, l1w, l1b, l2w, l2b, out);
}